// Round 2
// baseline (95.717 us; speedup 1.0000x reference)
//
#include <hip/hip_runtime.h>

// Fused SNN forward: one block = one batch column b.
//   Phase A: c[t,o] = dot(x[t,b,:], W[o,:])  for t=0..63 (GEMM, HBM-bound)
//   Phase B: IF-neuron scan over t in LDS, write out[b,:] = mean_t(spike)
//
// x staged global->LDS via global_load_lds (bytes-in-flight without VGPRs),
// per-wave counted vmcnt double-buffer pipeline, no barriers in main loop.
// LDS x layout uses an XOR-4 source-side swizzle so the strided reads are
// <=2-way bank conflicts (free) while the DMA destination stays linear.

#define T_STEPS 64
#define BATCH   2048
#define FEAT    784
#define OUT_N   10

typedef __attribute__((address_space(1))) const void GV;
typedef __attribute__((address_space(3))) void LV;

__device__ __forceinline__ void gld16(const float* src, float* dst) {
    __builtin_amdgcn_global_load_lds((GV*)src, (LV*)dst, 16, 0, 0);
}

__global__ __launch_bounds__(256, 2)
void snn_fused(const float* __restrict__ x, const float* __restrict__ W,
               const float* __restrict__ bias, float* __restrict__ out) {
    __shared__ float  Wl[OUT_N * FEAT];        // 31360 B, [o][f]
    __shared__ float4 xbuf[4][2][16][16];      // 32768 B, [wave][dbuf][t'][fq]
    __shared__ float4 xtail[4][16][4];         // 4096 B,  [wave][t'][fq] feats 768..783
    __shared__ float  c_sh[T_STEPS][12];       // 3072 B, padded rows (48 B, 16-aligned)

    const int tid = threadIdx.x;
    const int w   = tid >> 6;        // wave 0..3 -> t rows [w*16, w*16+16)
    const int ln  = tid & 63;
    const int l16 = ln & 15;         // feature slice
    const int r   = ln >> 4;         // row slot (4 rows each via g)
    const int b   = blockIdx.x;

    // ---- stage W into LDS: 1960 float4s, 16 B/thread/call ----
#pragma unroll
    for (int k = 0; k < 7; ++k)
        gld16(W + (size_t)(k * 256 + tid) * 4, &Wl[(size_t)(k * 256 + w * 64) * 4]);
    if (tid < 168)
        gld16(W + (size_t)(1792 + tid) * 4, &Wl[(size_t)(1792 + w * 64) * 4]);
    __syncthreads();   // compiler drains vmcnt here -> W ready; x not yet issued

    const size_t rowstride = (size_t)BATCH * FEAT;      // floats per t step
    const float* xb = x + (size_t)b * FEAT;

    // stage tail chunk (feats 768..783): lane -> (t'=ln>>2, fq=ln&3), 1 call
    gld16(xb + (size_t)(w * 16 + (ln >> 2)) * rowstride + 768 + (ln & 3) * 4,
          (float*)&xtail[w][0][0]);

    // STAGE chunk c into xbuf[w][bufi]: 4 calls, call j covers t' = 4j..4j+3.
    // Source fq is XORed with (j<<2) (wave-uniform per call) = the swizzle key
    // the reader re-applies; LDS destination stays linear.
#define STAGE(c, bufi) do {                                                   \
        _Pragma("unroll")                                                     \
        for (int j = 0; j < 4; ++j) {                                         \
            const int tp  = 4 * j + (ln >> 4);                                \
            const int fqs = (ln & 15) ^ (j << 2);                             \
            gld16(xb + (size_t)(w * 16 + tp) * rowstride + (c) * 64 + fqs * 4,\
                  (float*)&xbuf[w][bufi][4 * j][0]);                          \
        }                                                                     \
    } while (0)

    STAGE(0, 0);

    float acc[4][OUT_N];
#pragma unroll
    for (int g = 0; g < 4; ++g)
#pragma unroll
        for (int o = 0; o < OUT_N; ++o) acc[g][o] = 0.0f;

#pragma unroll 1
    for (int c = 0; c < 12; ++c) {
        __builtin_amdgcn_sched_barrier(0);
        if (c < 11) {
            STAGE(c + 1, (c + 1) & 1);
            asm volatile("s_waitcnt vmcnt(4)" ::: "memory");  // tail + chunk c landed
        } else {
            asm volatile("s_waitcnt vmcnt(0)" ::: "memory");
        }
        __builtin_amdgcn_sched_barrier(0);

        float4 xf[4];
#pragma unroll
        for (int g = 0; g < 4; ++g)
            xf[g] = xbuf[w][c & 1][r * 4 + g][l16 ^ (r << 2)];  // swizzled read, 2-way max
#pragma unroll
        for (int o = 0; o < OUT_N; ++o) {
            const float4 wf = *(const float4*)&Wl[o * FEAT + c * 64 + l16 * 4];
#pragma unroll
            for (int g = 0; g < 4; ++g) {
                acc[g][o] = fmaf(xf[g].x, wf.x, acc[g][o]);
                acc[g][o] = fmaf(xf[g].y, wf.y, acc[g][o]);
                acc[g][o] = fmaf(xf[g].z, wf.z, acc[g][o]);
                acc[g][o] = fmaf(xf[g].w, wf.w, acc[g][o]);
            }
        }
    }

    // tail feats 768..783: lanes l16<4 add 4 floats each
    if (l16 < 4) {
        float4 xf[4];
#pragma unroll
        for (int g = 0; g < 4; ++g) xf[g] = xtail[w][r * 4 + g][l16];
#pragma unroll
        for (int o = 0; o < OUT_N; ++o) {
            const float4 wf = *(const float4*)&Wl[o * FEAT + 768 + l16 * 4];
#pragma unroll
            for (int g = 0; g < 4; ++g) {
                acc[g][o] = fmaf(xf[g].x, wf.x, acc[g][o]);
                acc[g][o] = fmaf(xf[g].y, wf.y, acc[g][o]);
                acc[g][o] = fmaf(xf[g].z, wf.z, acc[g][o]);
                acc[g][o] = fmaf(xf[g].w, wf.w, acc[g][o]);
            }
        }
    }

    // butterfly reduce across the 16 feature lanes
#pragma unroll
    for (int g = 0; g < 4; ++g)
#pragma unroll
        for (int o = 0; o < OUT_N; ++o) {
            float v = acc[g][o];
            v += __shfl_xor(v, 1, 64);
            v += __shfl_xor(v, 2, 64);
            v += __shfl_xor(v, 4, 64);
            v += __shfl_xor(v, 8, 64);
            acc[g][o] = v;
        }

    if (l16 == 0) {
#pragma unroll
        for (int g = 0; g < 4; ++g) {
            const int t = w * 16 + r * 4 + g;
            *(float4*)&c_sh[t][0] = make_float4(acc[g][0], acc[g][1], acc[g][2], acc[g][3]);
            *(float4*)&c_sh[t][4] = make_float4(acc[g][4], acc[g][5], acc[g][6], acc[g][7]);
            *(float2*)&c_sh[t][8] = make_float2(acc[g][8], acc[g][9]);
        }
    }
    __syncthreads();

    // Phase B: IF-neuron scan, 10 lanes (one per output unit)
    if (tid < OUT_N) {
        const float bo = bias[tid];
        float v = 0.0f, cnt = 0.0f;
#pragma unroll
        for (int t = 0; t < T_STEPS; ++t) {
            const float vv = v + c_sh[t][tid] + bo;
            const bool  s  = (vv >= 1.0f);
            cnt += s ? 1.0f : 0.0f;
            v = s ? 0.0f : vv;
        }
        out[b * OUT_N + tid] = cnt * (1.0f / 64.0f);
    }
#undef STAGE
}

extern "C" void kernel_launch(void* const* d_in, const int* in_sizes, int n_in,
                              void* d_out, int out_size, void* d_ws, size_t ws_size,
                              hipStream_t stream) {
    const float* x    = (const float*)d_in[0];   // [64, 2048, 784] f32
    const float* W    = (const float*)d_in[1];   // [10, 784] f32
    const float* bias = (const float*)d_in[2];   // [10] f32
    float* out = (float*)d_out;                  // [2048, 10] f32

    snn_fused<<<dim3(BATCH), dim3(256), 0, stream>>>(x, W, bias, out);
}